// Round 6
// baseline (507.018 us; speedup 1.0000x reference)
//
#include <hip/hip_runtime.h>

#define IN_F 256
#define OUT_F 64
#define NBKT_MAX 1024          // buckets of 64 dst nodes; supports N <= 65536
#define PART_BLOCKS 128

typedef __attribute__((ext_vector_type(8))) short short8;
typedef __attribute__((ext_vector_type(4))) float f32x4;
typedef unsigned int uint32;

#define AS_I(f) __builtin_bit_cast(int, f)
#define AS_F(i) __builtin_bit_cast(float, i)
#define DPP_ADD(v, ctrl, rmask) \
    v += AS_F(__builtin_amdgcn_update_dpp(0, AS_I(v), ctrl, rmask, 0xf, true))

// Full 64-lane sum broadcast (pure VALU pipe / DPP).
__device__ __forceinline__ float wave_sum_bcast(float p) {
    DPP_ADD(p, 0x111, 0xf);  // row_shr:1
    DPP_ADD(p, 0x112, 0xf);  // row_shr:2
    DPP_ADD(p, 0x114, 0xf);  // row_shr:4
    DPP_ADD(p, 0x118, 0xf);  // row_shr:8
    DPP_ADD(p, 0x142, 0xa);  // row_bcast:15
    DPP_ADD(p, 0x143, 0xc);  // row_bcast:31
    return AS_F(__builtin_amdgcn_readlane(AS_I(p), 63));
}

__device__ __forceinline__ unsigned short f2bf(float f) {  // RNE f32->bf16
    uint32 u = __builtin_bit_cast(uint32, f);
    u += 0x7fffu + ((u >> 16) & 1u);
    return (unsigned short)(u >> 16);
}
__device__ __forceinline__ float bf2f(unsigned short s) {
    return __builtin_bit_cast(float, (uint32)s << 16);
}

// ---------------------------------------------------------------------------
// Bucket histogram (LDS-staged: 782 counters/block, then one global atomic
// per nonzero bucket) + wprep on blocks 0..7 (bf16 B-fragment layout wT2).
// ---------------------------------------------------------------------------
__global__ __launch_bounds__(256) void hist_wprep_kernel(const int* __restrict__ dst,
                                                         int* __restrict__ bkt_cnt, int E,
                                                         const float* __restrict__ w,
                                                         unsigned short* __restrict__ wt2,
                                                         int NB) {
    __shared__ int lcnt[NBKT_MAX];
    int b = blockIdx.x, t = threadIdx.x;
    for (int i = t; i < NB; i += 256) lcnt[i] = 0;
    __syncthreads();

    if (b < 8) {
        int slot = b * 256 + t;            // 2048 slots = 32 kb * 64 n
        int kb = slot >> 6, n = slot & 63;
        short8 v;
#pragma unroll
        for (int j = 0; j < 8; ++j)
            v[j] = (short)f2bf(w[(size_t)(kb * 8 + j) * OUT_F + n]);
        *(short8*)(wt2 + (size_t)slot * 8) = v;
    }

    for (int e = b * 256 + t; e < E; e += gridDim.x * 256)
        atomicAdd(&lcnt[dst[e] >> 6], 1);
    __syncthreads();
    for (int i = t; i < NB; i += 256)
        if (lcnt[i]) atomicAdd(&bkt_cnt[i], lcnt[i]);
}

// ---------------------------------------------------------------------------
// Single-block exclusive scan of NB (<=1024) bucket counts -> base & cursor.
// ---------------------------------------------------------------------------
__global__ __launch_bounds__(1024) void scan_buckets(const int* __restrict__ cnt,
                                                     int* __restrict__ base,
                                                     int* __restrict__ cursor,
                                                     int NB, int E) {
    __shared__ int wsum[16], woff[16];
    int t = threadIdx.x, lane = t & 63, wid = t >> 6;
    int v = (t < NB) ? cnt[t] : 0;
    int x = v;
#pragma unroll
    for (int off = 1; off < 64; off <<= 1) {
        int y = __shfl_up(x, off, 64);
        if (lane >= off) x += y;
    }
    if (lane == 63) wsum[wid] = x;
    __syncthreads();
    if (t < 16) {
        int s = wsum[t], xs = s;
#pragma unroll
        for (int off = 1; off < 16; off <<= 1) {
            int y = __shfl_up(xs, off, 64);
            if (t >= off) xs += y;
        }
        woff[t] = xs - s;
    }
    __syncthreads();
    int excl = woff[wid] + x - v;
    if (t < NB) { base[t] = excl; cursor[t] = excl; }
    if (t == 0) base[NB] = E;
}

// ---------------------------------------------------------------------------
// Partition: each block handles a contiguous edge chunk; LDS-count its chunk,
// reserve per-bucket contiguous ranges with ONE atomic per (block,bucket),
// then place packed (dstLocal<<26 | src) words. Writes land in contiguous
// per-(block,bucket) runs inside hot bucket regions -> low amplification.
// ---------------------------------------------------------------------------
__global__ __launch_bounds__(256) void partition_kernel(const int* __restrict__ src,
                                                        const int* __restrict__ dst,
                                                        int* __restrict__ bkt_cursor,
                                                        uint32* __restrict__ pairs,
                                                        int E, int NB) {
    __shared__ int lcnt[NBKT_MAX];
    __shared__ int gbase[NBKT_MAX];
    int t = threadIdx.x;
    int chunk = (E + gridDim.x - 1) / gridDim.x;
    int s0 = blockIdx.x * chunk;
    int s1 = min(E, s0 + chunk);

    for (int i = t; i < NB; i += 256) lcnt[i] = 0;
    __syncthreads();
    for (int e = s0 + t; e < s1; e += 256)
        atomicAdd(&lcnt[dst[e] >> 6], 1);
    __syncthreads();
    for (int i = t; i < NB; i += 256) {
        int c = lcnt[i];
        if (c) gbase[i] = atomicAdd(&bkt_cursor[i], c);
        lcnt[i] = 0;
    }
    __syncthreads();
    for (int e = s0 + t; e < s1; e += 256) {
        int d  = dst[e];
        int bk = d >> 6;
        int idx = atomicAdd(&lcnt[bk], 1);
        pairs[gbase[bk] + idx] = (uint32)src[e] | ((uint32)(d & 63) << 26);
    }
}

// ---------------------------------------------------------------------------
// GEMM hp_bf16 = bf16(h @ w) via MFMA 16x16x32 bf16. NO LDS, NO barriers.
// (verified R5: absmax 4.0 vs threshold 19.44)
// ---------------------------------------------------------------------------
__global__ __launch_bounds__(256) void gemm_kernel(const float* __restrict__ h,
                                                   const unsigned short* __restrict__ wt2,
                                                   unsigned short* __restrict__ hpb, int N) {
    int tid  = threadIdx.x;
    int wave = tid >> 6, lane = tid & 63;
    int n16  = lane & 15, quad = lane >> 4;

    int base = blockIdx.x * 64 + wave * 16;
    int arow_i = base + n16; if (arow_i >= N) arow_i = N - 1;
    const float* arow = h + (size_t)arow_i * IN_F;

    f32x4 acc[4];
#pragma unroll
    for (int ct = 0; ct < 4; ++ct) acc[ct] = (f32x4){0.f, 0.f, 0.f, 0.f};

#pragma unroll
    for (int ks = 0; ks < 8; ++ks) {
        int k0 = ks * 32;
        float4 a0 = *(const float4*)(arow + k0 + quad * 8);
        float4 a1 = *(const float4*)(arow + k0 + quad * 8 + 4);
        short8 af;
        af[0] = (short)f2bf(a0.x); af[1] = (short)f2bf(a0.y);
        af[2] = (short)f2bf(a0.z); af[3] = (short)f2bf(a0.w);
        af[4] = (short)f2bf(a1.x); af[5] = (short)f2bf(a1.y);
        af[6] = (short)f2bf(a1.z); af[7] = (short)f2bf(a1.w);
        int kb = ks * 4 + quad;
#pragma unroll
        for (int ct = 0; ct < 4; ++ct) {
            short8 bf = *(const short8*)(wt2 + (size_t)(kb * 64 + ct * 16 + n16) * 8);
            acc[ct] = __builtin_amdgcn_mfma_f32_16x16x32_bf16(af, bf, acc[ct], 0, 0, 0);
        }
    }

#pragma unroll
    for (int ct = 0; ct < 4; ++ct) {
#pragma unroll
        for (int r = 0; r < 4; ++r) {
            int ro = base + quad * 4 + r;
            if (ro < N) hpb[(size_t)ro * OUT_F + ct * 16 + n16] = f2bf(acc[ct][r]);
        }
    }
}

// ---------------------------------------------------------------------------
// Accumulate per bucket: block = 64 dst nodes. acc[64][64] f32 + hd[64][64]
// f32 in LDS. Per edge: gather hpb[src] row, DPP dot vs LDS hd, ds_add_f32
// into LDS acc. Epilogue fuses *sum(attw) and deg==0 fallback.
// ---------------------------------------------------------------------------
__global__ __launch_bounds__(256) void accum_bucket_kernel(const unsigned short* __restrict__ hpb,
                                                           const uint32* __restrict__ pairs,
                                                           const int* __restrict__ bkt_base,
                                                           const float* __restrict__ attw,
                                                           float* __restrict__ out, int N) {
    __shared__ float accS[64 * 64];
    __shared__ float hdS[64 * 64];
    __shared__ int   cntS[64];

    int b = blockIdx.x, t = threadIdx.x;
    int wave = t >> 6, lane = t & 63;
    int node0 = b * 64;

    for (int i = t; i < 64 * 64; i += 256) {
        accS[i] = 0.f;
        int node = node0 + (i >> 6);
        hdS[i] = (node < N) ? bf2f(hpb[(size_t)node * OUT_F + (i & 63)]) : 0.f;
    }
    if (t < 64) cntS[t] = 0;
    __syncthreads();

    int beg = bkt_base[b], end = bkt_base[b + 1];
    int nE = end - beg;
    int quarter = (nE + 3) >> 2;
    int js = beg + wave * quarter;
    int je = min(js + quarter, end);

    float c = 0.f;
#pragma unroll
    for (int i = 0; i < 8; ++i) c += attw[i];

    int j = js;
    for (; j + 8 <= je; j += 8) {
        uint32 p[8]; float a[8], hv[8], d[8]; int dl[8];
#pragma unroll
        for (int u = 0; u < 8; ++u) p[u] = pairs[j + u];
#pragma unroll
        for (int u = 0; u < 8; ++u) {
            int s = (int)(p[u] & 0x3FFFFFFu);
            dl[u] = (int)(p[u] >> 26);
            a[u] = bf2f(hpb[(size_t)s * OUT_F + lane]);
        }
#pragma unroll
        for (int u = 0; u < 8; ++u) hv[u] = hdS[dl[u] * 64 + lane];
#pragma unroll
        for (int u = 0; u < 8; ++u) d[u] = wave_sum_bcast(a[u] * hv[u]);
#pragma unroll
        for (int u = 0; u < 8; ++u) atomicAdd(&accS[dl[u] * 64 + lane], d[u] * a[u]);
#pragma unroll
        for (int u = 0; u < 8; ++u) if (lane == 0) atomicAdd(&cntS[dl[u]], 1);
    }
    for (; j < je; ++j) {
        uint32 p = pairs[j];
        int s  = (int)(p & 0x3FFFFFFu);
        int dl = (int)(p >> 26);
        float a  = bf2f(hpb[(size_t)s * OUT_F + lane]);
        float d  = wave_sum_bcast(a * hdS[dl * 64 + lane]);
        atomicAdd(&accS[dl * 64 + lane], d * a);
        if (lane == 0) atomicAdd(&cntS[dl], 1);
    }
    __syncthreads();

    for (int i = t; i < 64 * 64; i += 256) {
        int node = node0 + (i >> 6);
        if (node < N)
            out[(size_t)node * OUT_F + (i & 63)] = cntS[i >> 6] ? accS[i] * c : hdS[i];
    }
}

extern "C" void kernel_launch(void* const* d_in, const int* in_sizes, int n_in,
                              void* d_out, int out_size, void* d_ws, size_t ws_size,
                              hipStream_t stream) {
    const float* h    = (const float*)d_in[0];
    const float* w    = (const float*)d_in[1];
    const float* attw = (const float*)d_in[2];
    const int*   src  = (const int*)d_in[3];
    const int*   dst  = (const int*)d_in[4];

    int N = in_sizes[0] / IN_F;
    int E = in_sizes[3];
    int NB = (N + 63) >> 6;    // 782 for N=50000 (NB <= NBKT_MAX)

    float* out = (float*)d_out;

    char* p = (char*)d_ws;
    unsigned short* hpb = (unsigned short*)p;  p += (size_t)N * OUT_F * sizeof(unsigned short);
    unsigned short* wt2 = (unsigned short*)p;  p += (size_t)2048 * 8 * sizeof(unsigned short);
    int* bkt_cnt    = (int*)p;                 p += (NBKT_MAX + 1) * sizeof(int);
    int* bkt_base   = (int*)p;                 p += (NBKT_MAX + 1) * sizeof(int);
    int* bkt_cursor = (int*)p;                 p += (NBKT_MAX + 1) * sizeof(int);
    uint32* pairs   = (uint32*)p;

    hipMemsetAsync(bkt_cnt, 0, (NB + 1) * sizeof(int), stream);

    hist_wprep_kernel<<<256, 256, 0, stream>>>(dst, bkt_cnt, E, w, wt2, NB);

    gemm_kernel<<<(N + 63) / 64, 256, 0, stream>>>(h, wt2, hpb, N);

    scan_buckets<<<1, 1024, 0, stream>>>(bkt_cnt, bkt_base, bkt_cursor, NB, E);

    partition_kernel<<<PART_BLOCKS, 256, 0, stream>>>(src, dst, bkt_cursor, pairs, E, NB);

    accum_bucket_kernel<<<NB, 256, 0, stream>>>(hpb, pairs, bkt_base, attw, out, N);
}

// Round 7
// 183.423 us; speedup vs baseline: 2.7642x; 2.7642x over previous
//
#include <hip/hip_runtime.h>

#define IN_F 256
#define OUT_F 64
#define NBKT_MAX 1024          // buckets of 64 dst nodes; supports N <= 65536
#define PART_BLOCKS 128

typedef __attribute__((ext_vector_type(8))) short short8;
typedef __attribute__((ext_vector_type(4))) float f32x4;
typedef unsigned int uint32;

#define AS_I(f) __builtin_bit_cast(int, f)
#define AS_F(i) __builtin_bit_cast(float, i)
#define DPP_ADD(v, ctrl, rmask) \
    v += AS_F(__builtin_amdgcn_update_dpp(0, AS_I(v), ctrl, rmask, 0xf, true))

// Full 64-lane sum broadcast (pure VALU pipe / DPP).
__device__ __forceinline__ float wave_sum_bcast(float p) {
    DPP_ADD(p, 0x111, 0xf);  // row_shr:1
    DPP_ADD(p, 0x112, 0xf);  // row_shr:2
    DPP_ADD(p, 0x114, 0xf);  // row_shr:4
    DPP_ADD(p, 0x118, 0xf);  // row_shr:8
    DPP_ADD(p, 0x142, 0xa);  // row_bcast:15
    DPP_ADD(p, 0x143, 0xc);  // row_bcast:31
    return AS_F(__builtin_amdgcn_readlane(AS_I(p), 63));
}

__device__ __forceinline__ unsigned short f2bf(float f) {  // RNE f32->bf16
    uint32 u = __builtin_bit_cast(uint32, f);
    u += 0x7fffu + ((u >> 16) & 1u);
    return (unsigned short)(u >> 16);
}
__device__ __forceinline__ float bf2f(unsigned short s) {
    return __builtin_bit_cast(float, (uint32)s << 16);
}

// ---------------------------------------------------------------------------
// Bucket histogram (LDS-staged) + wprep on blocks 0..7 (bf16 B-frag wT2).
// ---------------------------------------------------------------------------
__global__ __launch_bounds__(256) void hist_wprep_kernel(const int* __restrict__ dst,
                                                         int* __restrict__ bkt_cnt, int E,
                                                         const float* __restrict__ w,
                                                         unsigned short* __restrict__ wt2,
                                                         int NB) {
    __shared__ int lcnt[NBKT_MAX];
    int b = blockIdx.x, t = threadIdx.x;
    for (int i = t; i < NB; i += 256) lcnt[i] = 0;
    __syncthreads();

    if (b < 8) {
        int slot = b * 256 + t;            // 2048 slots = 32 kb * 64 n
        int kb = slot >> 6, n = slot & 63;
        short8 v;
#pragma unroll
        for (int j = 0; j < 8; ++j)
            v[j] = (short)f2bf(w[(size_t)(kb * 8 + j) * OUT_F + n]);
        *(short8*)(wt2 + (size_t)slot * 8) = v;
    }

    for (int e = b * 256 + t; e < E; e += gridDim.x * 256)
        atomicAdd(&lcnt[dst[e] >> 6], 1);
    __syncthreads();
    for (int i = t; i < NB; i += 256)
        if (lcnt[i]) atomicAdd(&bkt_cnt[i], lcnt[i]);
}

// ---------------------------------------------------------------------------
// Single-block exclusive scan of NB (<=1024) bucket counts -> base & cursor.
// ---------------------------------------------------------------------------
__global__ __launch_bounds__(1024) void scan_buckets(const int* __restrict__ cnt,
                                                     int* __restrict__ base,
                                                     int* __restrict__ cursor,
                                                     int NB, int E) {
    __shared__ int wsum[16], woff[16];
    int t = threadIdx.x, lane = t & 63, wid = t >> 6;
    int v = (t < NB) ? cnt[t] : 0;
    int x = v;
#pragma unroll
    for (int off = 1; off < 64; off <<= 1) {
        int y = __shfl_up(x, off, 64);
        if (lane >= off) x += y;
    }
    if (lane == 63) wsum[wid] = x;
    __syncthreads();
    if (t < 16) {
        int s = wsum[t], xs = s;
#pragma unroll
        for (int off = 1; off < 16; off <<= 1) {
            int y = __shfl_up(xs, off, 64);
            if (t >= off) xs += y;
        }
        woff[t] = xs - s;
    }
    __syncthreads();
    int excl = woff[wid] + x - v;
    if (t < NB) { base[t] = excl; cursor[t] = excl; }
    if (t == 0) base[NB] = E;
}

// ---------------------------------------------------------------------------
// Partition: block-local LDS counts -> ONE global atomic per (block,bucket)
// -> contiguous per-(block,bucket) runs of packed (dstLocal<<26 | src).
// ---------------------------------------------------------------------------
__global__ __launch_bounds__(256) void partition_kernel(const int* __restrict__ src,
                                                        const int* __restrict__ dst,
                                                        int* __restrict__ bkt_cursor,
                                                        uint32* __restrict__ pairs,
                                                        int E, int NB) {
    __shared__ int lcnt[NBKT_MAX];
    __shared__ int gbase[NBKT_MAX];
    int t = threadIdx.x;
    int chunk = (E + gridDim.x - 1) / gridDim.x;
    int s0 = blockIdx.x * chunk;
    int s1 = min(E, s0 + chunk);

    for (int i = t; i < NB; i += 256) lcnt[i] = 0;
    __syncthreads();
    for (int e = s0 + t; e < s1; e += 256)
        atomicAdd(&lcnt[dst[e] >> 6], 1);
    __syncthreads();
    for (int i = t; i < NB; i += 256) {
        int c = lcnt[i];
        if (c) gbase[i] = atomicAdd(&bkt_cursor[i], c);
        lcnt[i] = 0;
    }
    __syncthreads();
    for (int e = s0 + t; e < s1; e += 256) {
        int d  = dst[e];
        int bk = d >> 6;
        int idx = atomicAdd(&lcnt[bk], 1);
        pairs[gbase[bk] + idx] = (uint32)src[e] | ((uint32)(d & 63) << 26);
    }
}

// ---------------------------------------------------------------------------
// Per-bucket LDS counting sort (64 bins, native int LDS atomics):
// bucket-sorted pairs -> node-sorted srcs + node-level row_ptr.
// One block owns one ~4KB output region -> writes stay L2-hot (amp ~1x).
// ---------------------------------------------------------------------------
__global__ __launch_bounds__(256) void sortlocal_kernel(const uint32* __restrict__ pairs,
                                                        const int* __restrict__ bkt_base,
                                                        int* __restrict__ srcs,
                                                        int* __restrict__ row_ptr,
                                                        int N, int E) {
    __shared__ int bin[64], excl[65], cur[64];
    int b = blockIdx.x, t = threadIdx.x;
    int beg = bkt_base[b], end = bkt_base[b + 1];

    if (t < 64) bin[t] = 0;
    __syncthreads();
    for (int i = beg + t; i < end; i += 256)
        atomicAdd(&bin[pairs[i] >> 26], 1);
    __syncthreads();
    if (t < 64) {                       // wave-0 exclusive scan of 64 bins
        int v = bin[t], x = v;
#pragma unroll
        for (int off = 1; off < 64; off <<= 1) {
            int y = __shfl_up(x, off, 64);
            if (t >= off) x += y;
        }
        excl[t] = x - v;
        cur[t]  = x - v;
        if (t == 63) excl[64] = x;
    }
    __syncthreads();
    if (t < 65) {
        int idx = b * 64 + t;
        if (idx <= N) row_ptr[idx] = beg + excl[t];
    }
    for (int i = beg + t; i < end; i += 256) {
        uint32 p = pairs[i];
        int dl   = (int)(p >> 26);
        int pos  = atomicAdd(&cur[dl], 1);
        srcs[beg + pos] = (int)(p & 0x3FFFFFFu);
    }
}

// ---------------------------------------------------------------------------
// GEMM hp_bf16 = bf16(h @ w) via MFMA 16x16x32 bf16. NO LDS, NO barriers.
// (verified R5/R6: absmax 4.0 vs threshold 19.44)
// ---------------------------------------------------------------------------
__global__ __launch_bounds__(256) void gemm_kernel(const float* __restrict__ h,
                                                   const unsigned short* __restrict__ wt2,
                                                   unsigned short* __restrict__ hpb, int N) {
    int tid  = threadIdx.x;
    int wave = tid >> 6, lane = tid & 63;
    int n16  = lane & 15, quad = lane >> 4;

    int base = blockIdx.x * 64 + wave * 16;
    int arow_i = base + n16; if (arow_i >= N) arow_i = N - 1;
    const float* arow = h + (size_t)arow_i * IN_F;

    f32x4 acc[4];
#pragma unroll
    for (int ct = 0; ct < 4; ++ct) acc[ct] = (f32x4){0.f, 0.f, 0.f, 0.f};

#pragma unroll
    for (int ks = 0; ks < 8; ++ks) {
        int k0 = ks * 32;
        float4 a0 = *(const float4*)(arow + k0 + quad * 8);
        float4 a1 = *(const float4*)(arow + k0 + quad * 8 + 4);
        short8 af;
        af[0] = (short)f2bf(a0.x); af[1] = (short)f2bf(a0.y);
        af[2] = (short)f2bf(a0.z); af[3] = (short)f2bf(a0.w);
        af[4] = (short)f2bf(a1.x); af[5] = (short)f2bf(a1.y);
        af[6] = (short)f2bf(a1.z); af[7] = (short)f2bf(a1.w);
        int kb = ks * 4 + quad;
#pragma unroll
        for (int ct = 0; ct < 4; ++ct) {
            short8 bf = *(const short8*)(wt2 + (size_t)(kb * 64 + ct * 16 + n16) * 8);
            acc[ct] = __builtin_amdgcn_mfma_f32_16x16x32_bf16(af, bf, acc[ct], 0, 0, 0);
        }
    }

#pragma unroll
    for (int ct = 0; ct < 4; ++ct) {
#pragma unroll
        for (int r = 0; r < 4; ++r) {
            int ro = base + quad * 4 + r;
            if (ro < N) hpb[(size_t)ro * OUT_F + ct * 16 + n16] = f2bf(acc[ct][r]);
        }
    }
}

// ---------------------------------------------------------------------------
// Accumulate (R5-proven): one wave per dst node, lane = feature. bf16 hp
// gathers, 8 independent gather+DPP chains, register accumulate.
// ---------------------------------------------------------------------------
__global__ __launch_bounds__(256) void accum_kernel(const unsigned short* __restrict__ hpb,
                                                    const int* __restrict__ row_ptr,
                                                    const int* __restrict__ srcs,
                                                    const float* __restrict__ attw,
                                                    float* __restrict__ out, int N) {
    int v    = (blockIdx.x * blockDim.x + threadIdx.x) >> 6;
    int lane = threadIdx.x & 63;
    if (v >= N) return;

    int beg = row_ptr[v];
    int end = row_ptr[v + 1];
    float hd = bf2f(hpb[(size_t)v * OUT_F + lane]);

    float c = 0.f;
#pragma unroll
    for (int i = 0; i < 8; ++i) c += attw[i];

    float acc = 0.f;
    int j = beg;
    for (; j + 8 <= end; j += 8) {
        float a[8];
#pragma unroll
        for (int u = 0; u < 8; ++u) {
            int s = srcs[j + u];
            a[u] = bf2f(hpb[(size_t)s * OUT_F + lane]);
        }
        float d[8];
#pragma unroll
        for (int u = 0; u < 8; ++u) d[u] = wave_sum_bcast(a[u] * hd);
#pragma unroll
        for (int u = 0; u < 8; ++u) acc = fmaf(d[u], a[u], acc);
    }
    for (; j + 4 <= end; j += 4) {
        float a[4];
#pragma unroll
        for (int u = 0; u < 4; ++u) {
            int s = srcs[j + u];
            a[u] = bf2f(hpb[(size_t)s * OUT_F + lane]);
        }
        float d[4];
#pragma unroll
        for (int u = 0; u < 4; ++u) d[u] = wave_sum_bcast(a[u] * hd);
#pragma unroll
        for (int u = 0; u < 4; ++u) acc = fmaf(d[u], a[u], acc);
    }
    for (; j < end; ++j) {
        int s = srcs[j];
        float a = bf2f(hpb[(size_t)s * OUT_F + lane]);
        acc = fmaf(wave_sum_bcast(a * hd), a, acc);
    }

    out[(size_t)v * OUT_F + lane] = (end > beg) ? acc * c : hd;
}

extern "C" void kernel_launch(void* const* d_in, const int* in_sizes, int n_in,
                              void* d_out, int out_size, void* d_ws, size_t ws_size,
                              hipStream_t stream) {
    const float* h    = (const float*)d_in[0];
    const float* w    = (const float*)d_in[1];
    const float* attw = (const float*)d_in[2];
    const int*   src  = (const int*)d_in[3];
    const int*   dst  = (const int*)d_in[4];

    int N = in_sizes[0] / IN_F;
    int E = in_sizes[3];
    int NB = (N + 63) >> 6;    // 782 for N=50000 (NB <= NBKT_MAX)

    float* out = (float*)d_out;

    char* p = (char*)d_ws;
    unsigned short* hpb = (unsigned short*)p;  p += (size_t)N * OUT_F * sizeof(unsigned short);
    unsigned short* wt2 = (unsigned short*)p;  p += (size_t)2048 * 8 * sizeof(unsigned short);
    int* bkt_cnt    = (int*)p;                 p += (NBKT_MAX + 1) * sizeof(int);
    int* bkt_base   = (int*)p;                 p += (NBKT_MAX + 1) * sizeof(int);
    int* bkt_cursor = (int*)p;                 p += (NBKT_MAX + 1) * sizeof(int);
    int* row_ptr    = (int*)p;                 p += ((size_t)N + 8) * sizeof(int);
    uint32* pairs   = (uint32*)p;              p += (size_t)E * sizeof(uint32);
    int* srcs       = (int*)p;

    hipMemsetAsync(bkt_cnt, 0, (NB + 1) * sizeof(int), stream);

    hist_wprep_kernel<<<256, 256, 0, stream>>>(dst, bkt_cnt, E, w, wt2, NB);

    gemm_kernel<<<(N + 63) / 64, 256, 0, stream>>>(h, wt2, hpb, N);

    scan_buckets<<<1, 1024, 0, stream>>>(bkt_cnt, bkt_base, bkt_cursor, NB, E);

    partition_kernel<<<PART_BLOCKS, 256, 0, stream>>>(src, dst, bkt_cursor, pairs, E, NB);

    sortlocal_kernel<<<NB, 256, 0, stream>>>(pairs, bkt_base, srcs, row_ptr, N, E);

    accum_kernel<<<((size_t)N * 64 + 255) / 256, 256, 0, stream>>>(hpb, row_ptr, srcs, attw, out, N);
}

// Round 8
// 173.946 us; speedup vs baseline: 2.9148x; 1.0545x over previous
//
#include <hip/hip_runtime.h>

#define IN_F 256
#define OUT_F 64
#define NBKT_MAX 1024          // buckets of 64 dst nodes; supports N <= 65536
#define PART_BLOCKS 128
#define HIST_BLOCKS 256

typedef __attribute__((ext_vector_type(8))) short short8;
typedef __attribute__((ext_vector_type(4))) float f32x4;
typedef unsigned int uint32;

#define AS_I(f) __builtin_bit_cast(int, f)
#define AS_F(i) __builtin_bit_cast(float, i)
#define DPP_ADD(v, ctrl, rmask) \
    v += AS_F(__builtin_amdgcn_update_dpp(0, AS_I(v), ctrl, rmask, 0xf, true))

// Per-half (32-lane) sum: after row_shr 1/2/4/8 + row_bcast:15 (rows 1,3),
// lane31 = lanes0-31 sum, lane63 = lanes32-63 sum. Select by half.
__device__ __forceinline__ float half_sum_sel(float p, bool hi) {
    DPP_ADD(p, 0x111, 0xf);  // row_shr:1
    DPP_ADD(p, 0x112, 0xf);  // row_shr:2
    DPP_ADD(p, 0x114, 0xf);  // row_shr:4
    DPP_ADD(p, 0x118, 0xf);  // row_shr:8
    DPP_ADD(p, 0x142, 0xa);  // row_bcast:15 -> rows 1,3
    float dlo = AS_F(__builtin_amdgcn_readlane(AS_I(p), 31));
    float dhi = AS_F(__builtin_amdgcn_readlane(AS_I(p), 63));
    return hi ? dhi : dlo;
}

__device__ __forceinline__ unsigned short f2bf(float f) {  // RNE f32->bf16
    uint32 u = __builtin_bit_cast(uint32, f);
    u += 0x7fffu + ((u >> 16) & 1u);
    return (unsigned short)(u >> 16);
}
__device__ __forceinline__ float bf2f(unsigned short s) {
    return __builtin_bit_cast(float, (uint32)s << 16);
}

// ---------------------------------------------------------------------------
// FUSED: blocks [0,ngemm) do MFMA gemm (each block stages w -> bf16 B-frag
// table in its own LDS); blocks [ngemm, ngemm+HIST_BLOCKS) do the LDS-staged
// bucket histogram. Independent chains co-scheduled in one dispatch.
// ---------------------------------------------------------------------------
__global__ __launch_bounds__(256) void gemm_hist_kernel(const float* __restrict__ h,
                                                        const float* __restrict__ w,
                                                        unsigned short* __restrict__ hpb,
                                                        int N,
                                                        const int* __restrict__ dst,
                                                        int* __restrict__ bkt_cnt,
                                                        int E, int NB, int ngemm) {
    __shared__ char smem[32768];          // union: wfrag (gemm) / lcnt (hist)
    int b = blockIdx.x, t = threadIdx.x;

    if (b >= ngemm) {
        // ---- histogram path ----
        int* lcnt = (int*)smem;
        int hb = b - ngemm;
        for (int i = t; i < NB; i += 256) lcnt[i] = 0;
        __syncthreads();
        for (int e = hb * 256 + t; e < E; e += HIST_BLOCKS * 256)
            atomicAdd(&lcnt[dst[e] >> 6], 1);
        __syncthreads();
        for (int i = t; i < NB; i += 256)
            if (lcnt[i]) atomicAdd(&bkt_cnt[i], lcnt[i]);
        return;
    }

    // ---- gemm path: stage w as B-fragments (slot(kb,n) = bf16 w[kb*8..+7][n]) ----
    short8* wfrag = (short8*)smem;        // 2048 slots * 16B = 32 KB
    for (int slot = t; slot < 2048; slot += 256) {
        int kb = slot >> 6, n = slot & 63;
        short8 v;
#pragma unroll
        for (int jj = 0; jj < 8; ++jj)
            v[jj] = (short)f2bf(w[(size_t)(kb * 8 + jj) * OUT_F + n]);
        wfrag[slot] = v;
    }
    __syncthreads();

    int wave = t >> 6, lane = t & 63;
    int n16  = lane & 15, quad = lane >> 4;
    int base = b * 64 + wave * 16;
    int arow_i = base + n16; if (arow_i >= N) arow_i = N - 1;
    const float* arow = h + (size_t)arow_i * IN_F;

    f32x4 acc[4];
#pragma unroll
    for (int ct = 0; ct < 4; ++ct) acc[ct] = (f32x4){0.f, 0.f, 0.f, 0.f};

#pragma unroll
    for (int ks = 0; ks < 8; ++ks) {
        int k0 = ks * 32;
        float4 a0 = *(const float4*)(arow + k0 + quad * 8);
        float4 a1 = *(const float4*)(arow + k0 + quad * 8 + 4);
        short8 af;
        af[0] = (short)f2bf(a0.x); af[1] = (short)f2bf(a0.y);
        af[2] = (short)f2bf(a0.z); af[3] = (short)f2bf(a0.w);
        af[4] = (short)f2bf(a1.x); af[5] = (short)f2bf(a1.y);
        af[6] = (short)f2bf(a1.z); af[7] = (short)f2bf(a1.w);
        int kb = ks * 4 + quad;
#pragma unroll
        for (int ct = 0; ct < 4; ++ct) {
            short8 bf = wfrag[kb * 64 + ct * 16 + n16];
            acc[ct] = __builtin_amdgcn_mfma_f32_16x16x32_bf16(af, bf, acc[ct], 0, 0, 0);
        }
    }

#pragma unroll
    for (int ct = 0; ct < 4; ++ct) {
#pragma unroll
        for (int r = 0; r < 4; ++r) {
            int ro = base + quad * 4 + r;
            if (ro < N) hpb[(size_t)ro * OUT_F + ct * 16 + n16] = f2bf(acc[ct][r]);
        }
    }
}

// ---------------------------------------------------------------------------
// Single-block exclusive scan of NB (<=1024) bucket counts -> base & cursor.
// ---------------------------------------------------------------------------
__global__ __launch_bounds__(1024) void scan_buckets(const int* __restrict__ cnt,
                                                     int* __restrict__ base,
                                                     int* __restrict__ cursor,
                                                     int NB, int E) {
    __shared__ int wsum[16], woff[16];
    int t = threadIdx.x, lane = t & 63, wid = t >> 6;
    int v = (t < NB) ? cnt[t] : 0;
    int x = v;
#pragma unroll
    for (int off = 1; off < 64; off <<= 1) {
        int y = __shfl_up(x, off, 64);
        if (lane >= off) x += y;
    }
    if (lane == 63) wsum[wid] = x;
    __syncthreads();
    if (t < 16) {
        int s = wsum[t], xs = s;
#pragma unroll
        for (int off = 1; off < 16; off <<= 1) {
            int y = __shfl_up(xs, off, 64);
            if (t >= off) xs += y;
        }
        woff[t] = xs - s;
    }
    __syncthreads();
    int excl = woff[wid] + x - v;
    if (t < NB) { base[t] = excl; cursor[t] = excl; }
    if (t == 0) base[NB] = E;
}

// ---------------------------------------------------------------------------
// Partition: block-local LDS counts -> ONE global atomic per (block,bucket)
// -> contiguous per-(block,bucket) runs of packed (dstLocal<<26 | src).
// ---------------------------------------------------------------------------
__global__ __launch_bounds__(256) void partition_kernel(const int* __restrict__ src,
                                                        const int* __restrict__ dst,
                                                        int* __restrict__ bkt_cursor,
                                                        uint32* __restrict__ pairs,
                                                        int E, int NB) {
    __shared__ int lcnt[NBKT_MAX];
    __shared__ int gbase[NBKT_MAX];
    int t = threadIdx.x;
    int chunk = (E + gridDim.x - 1) / gridDim.x;
    int s0 = blockIdx.x * chunk;
    int s1 = min(E, s0 + chunk);

    for (int i = t; i < NB; i += 256) lcnt[i] = 0;
    __syncthreads();
    for (int e = s0 + t; e < s1; e += 256)
        atomicAdd(&lcnt[dst[e] >> 6], 1);
    __syncthreads();
    for (int i = t; i < NB; i += 256) {
        int c = lcnt[i];
        if (c) gbase[i] = atomicAdd(&bkt_cursor[i], c);
        lcnt[i] = 0;
    }
    __syncthreads();
    for (int e = s0 + t; e < s1; e += 256) {
        int d  = dst[e];
        int bk = d >> 6;
        int idx = atomicAdd(&lcnt[bk], 1);
        pairs[gbase[bk] + idx] = (uint32)src[e] | ((uint32)(d & 63) << 26);
    }
}

// ---------------------------------------------------------------------------
// Per-bucket LDS counting sort: bucket-sorted pairs -> node-sorted srcs +
// node-level row_ptr. Writes stay in the block's own ~4KB region (L2-hot).
// ---------------------------------------------------------------------------
__global__ __launch_bounds__(256) void sortlocal_kernel(const uint32* __restrict__ pairs,
                                                        const int* __restrict__ bkt_base,
                                                        int* __restrict__ srcs,
                                                        int* __restrict__ row_ptr,
                                                        int N, int E) {
    __shared__ int bin[64], excl[65], cur[64];
    int b = blockIdx.x, t = threadIdx.x;
    int beg = bkt_base[b], end = bkt_base[b + 1];

    if (t < 64) bin[t] = 0;
    __syncthreads();
    for (int i = beg + t; i < end; i += 256)
        atomicAdd(&bin[pairs[i] >> 26], 1);
    __syncthreads();
    if (t < 64) {
        int v = bin[t], x = v;
#pragma unroll
        for (int off = 1; off < 64; off <<= 1) {
            int y = __shfl_up(x, off, 64);
            if (t >= off) x += y;
        }
        excl[t] = x - v;
        cur[t]  = x - v;
        if (t == 63) excl[64] = x;
    }
    __syncthreads();
    if (t < 65) {
        int idx = b * 64 + t;
        if (idx <= N) row_ptr[idx] = beg + excl[t];
    }
    for (int i = beg + t; i < end; i += 256) {
        uint32 p = pairs[i];
        int dl   = (int)(p >> 26);
        int pos  = atomicAdd(&cur[dl], 1);
        srcs[beg + pos] = (int)(p & 0x3FFFFFFu);
    }
}

// ---------------------------------------------------------------------------
// Accumulate: one wave per dst node. Lane = (half, 2 features): lanes 0-31
// carry edge j, lanes 32-63 carry edge j+1 -> one dword gather fetches TWO
// edge rows (256B). 8 loads in flight = 16 edges MLP. DPP per-half reduce.
// ---------------------------------------------------------------------------
__global__ __launch_bounds__(256) void accum_kernel(const unsigned short* __restrict__ hpb,
                                                    const int* __restrict__ row_ptr,
                                                    const int* __restrict__ srcs,
                                                    const float* __restrict__ attw,
                                                    float* __restrict__ out, int N) {
    int v    = (blockIdx.x * blockDim.x + threadIdx.x) >> 6;
    int lane = threadIdx.x & 63;
    if (v >= N) return;

    int  half = lane & 31;
    bool hi   = lane >= 32;

    int beg = row_ptr[v];
    int end = row_ptr[v + 1];

    uint32 hd2 = *(const uint32*)(hpb + (size_t)v * OUT_F + half * 2);
    float hd0 = bf2f((unsigned short)(hd2 & 0xffff));
    float hd1 = bf2f((unsigned short)(hd2 >> 16));

    float c = 0.f;
#pragma unroll
    for (int i = 0; i < 8; ++i) c += attw[i];

    float acc0 = 0.f, acc1 = 0.f;
    int j = beg;

    for (; j + 16 <= end; j += 16) {        // 8 pair-loads = 16 edges in flight
        int4 s4[4];
#pragma unroll
        for (int u = 0; u < 4; ++u) s4[u] = ((const int4*)(srcs + j))[u];
        int slo[8], shi[8];
#pragma unroll
        for (int u = 0; u < 4; ++u) {
            slo[2 * u]     = s4[u].x; shi[2 * u]     = s4[u].y;
            slo[2 * u + 1] = s4[u].z; shi[2 * u + 1] = s4[u].w;
        }
        uint32 a2[8];
#pragma unroll
        for (int u = 0; u < 8; ++u) {
            int s = hi ? shi[u] : slo[u];
            a2[u] = *(const uint32*)(hpb + (size_t)s * OUT_F + half * 2);
        }
        float a0[8], a1[8], d[8];
#pragma unroll
        for (int u = 0; u < 8; ++u) {
            a0[u] = bf2f((unsigned short)(a2[u] & 0xffff));
            a1[u] = bf2f((unsigned short)(a2[u] >> 16));
            d[u]  = half_sum_sel(fmaf(a1[u], hd1, a0[u] * hd0), hi);
        }
#pragma unroll
        for (int u = 0; u < 8; ++u) {
            acc0 = fmaf(d[u], a0[u], acc0);
            acc1 = fmaf(d[u], a1[u], acc1);
        }
    }
    for (; j + 2 <= end; j += 2) {          // leftover pairs
        int s_lo = srcs[j], s_hi = srcs[j + 1];
        int s = hi ? s_hi : s_lo;
        uint32 a2 = *(const uint32*)(hpb + (size_t)s * OUT_F + half * 2);
        float a0 = bf2f((unsigned short)(a2 & 0xffff));
        float a1 = bf2f((unsigned short)(a2 >> 16));
        float d  = half_sum_sel(fmaf(a1, hd1, a0 * hd0), hi);
        acc0 = fmaf(d, a0, acc0);
        acc1 = fmaf(d, a1, acc1);
    }
    if (j < end) {                          // odd final edge: both halves load it,
        int s = srcs[j];                    // only the low half accumulates.
        uint32 a2 = *(const uint32*)(hpb + (size_t)s * OUT_F + half * 2);
        float a0 = bf2f((unsigned short)(a2 & 0xffff));
        float a1 = bf2f((unsigned short)(a2 >> 16));
        float d  = half_sum_sel(fmaf(a1, hd1, a0 * hd0), false);
        if (!hi) {
            acc0 = fmaf(d, a0, acc0);
            acc1 = fmaf(d, a1, acc1);
        }
    }

    // combine the two half-accumulators (features are duplicated across halves)
    acc0 += __shfl_xor(acc0, 32, 64);
    acc1 += __shfl_xor(acc1, 32, 64);

    if (!hi) {
        float r0, r1;
        if (end > beg) { r0 = acc0 * c; r1 = acc1 * c; }
        else           { r0 = hd0;      r1 = hd1;      }
        *(float2*)(out + (size_t)v * OUT_F + half * 2) = make_float2(r0, r1);
    }
}

extern "C" void kernel_launch(void* const* d_in, const int* in_sizes, int n_in,
                              void* d_out, int out_size, void* d_ws, size_t ws_size,
                              hipStream_t stream) {
    const float* h    = (const float*)d_in[0];
    const float* w    = (const float*)d_in[1];
    const float* attw = (const float*)d_in[2];
    const int*   src  = (const int*)d_in[3];
    const int*   dst  = (const int*)d_in[4];

    int N = in_sizes[0] / IN_F;
    int E = in_sizes[3];
    int NB = (N + 63) >> 6;    // 782 for N=50000 (NB <= NBKT_MAX)
    int ngemm = (N + 63) / 64;

    float* out = (float*)d_out;

    char* p = (char*)d_ws;
    unsigned short* hpb = (unsigned short*)p;  p += (size_t)N * OUT_F * sizeof(unsigned short);
    int* bkt_cnt    = (int*)p;                 p += (NBKT_MAX + 1) * sizeof(int);
    int* bkt_base   = (int*)p;                 p += (NBKT_MAX + 1) * sizeof(int);
    int* bkt_cursor = (int*)p;                 p += (NBKT_MAX + 1) * sizeof(int);
    int* row_ptr    = (int*)p;                 p += ((size_t)N + 8) * sizeof(int);
    uint32* pairs   = (uint32*)p;              p += (size_t)E * sizeof(uint32);
    int* srcs       = (int*)p;

    hipMemsetAsync(bkt_cnt, 0, (NB + 1) * sizeof(int), stream);

    gemm_hist_kernel<<<ngemm + HIST_BLOCKS, 256, 0, stream>>>(h, w, hpb, N,
                                                              dst, bkt_cnt, E, NB, ngemm);

    scan_buckets<<<1, 1024, 0, stream>>>(bkt_cnt, bkt_base, bkt_cursor, NB, E);

    partition_kernel<<<PART_BLOCKS, 256, 0, stream>>>(src, dst, bkt_cursor, pairs, E, NB);

    sortlocal_kernel<<<NB, 256, 0, stream>>>(pairs, bkt_base, srcs, row_ptr, N, E);

    accum_kernel<<<((size_t)N * 64 + 255) / 256, 256, 0, stream>>>(hpb, row_ptr, srcs, attw, out, N);
}